// Round 1
// baseline (300.031 us; speedup 1.0000x reference)
//
#include <hip/hip_runtime.h>
#include <hip/hip_bf16.h>
#include <stdint.h>

#define ALPHA 1.0f

typedef __attribute__((ext_vector_type(8))) short bf16x8;
typedef __attribute__((ext_vector_type(4))) float f32x4;

__device__ __forceinline__ unsigned short f32_to_bf16_rne(float f) {
    union { float f; unsigned int u; } v; v.f = f;
    unsigned int u = v.u;
    unsigned int r = u + 0x7FFFu + ((u >> 16) & 1u);
    return (unsigned short)(r >> 16);
}

__device__ __forceinline__ void async_copy16(const void* g, void* l) {
    __builtin_amdgcn_global_load_lds(
        (const __attribute__((address_space(1))) void*)g,
        (__attribute__((address_space(3))) void*)l, 16, 0, 0);
}

// ---------------------------------------------------------------------------
// Step 1a: t2[50][1024] = lora_up (50x4) @ (lora_down (4x100) @ down_aux (100x1024))
// One block, 1024 threads (one per column).
__global__ void lilora_t2_kernel(const float* __restrict__ lora_down,
                                 const float* __restrict__ lora_up,
                                 const float* __restrict__ down_aux,
                                 float* __restrict__ t2) {
    int i = threadIdx.x;  // 0..1023 column
    float t1[4] = {0.f, 0.f, 0.f, 0.f};
    for (int d = 0; d < 100; ++d) {
        float da = down_aux[d * 1024 + i];
#pragma unroll
        for (int r = 0; r < 4; ++r) t1[r] += lora_down[r * 100 + d] * da;
    }
    for (int u = 0; u < 50; ++u) {
        float acc = 0.f;
#pragma unroll
        for (int r = 0; r < 4; ++r) acc += lora_up[u * 4 + r] * t1[r];
        t2[u * 1024 + i] = acc;
    }
}

// ---------------------------------------------------------------------------
// Step 1b: W_eff[o][i] = W[o][i] + ALPHA * sum_u up_aux[o][u] * t2[u][i]  (bf16 out)
__global__ __launch_bounds__(256)
void weff_bf16_kernel(const float* __restrict__ W, const float* __restrict__ up_aux,
                      const float* __restrict__ t2, unsigned short* __restrict__ weff) {
    int o = blockIdx.x;
    int i0 = threadIdx.x * 4;
    float4 acc = *(const float4*)(W + (long)o * 1024 + i0);
    for (int u = 0; u < 50; ++u) {
        float s = up_aux[o * 50 + u] * ALPHA;
        float4 t = *(const float4*)(t2 + u * 1024 + i0);
        acc.x += s * t.x; acc.y += s * t.y; acc.z += s * t.z; acc.w += s * t.w;
    }
    ushort4 r;
    r.x = f32_to_bf16_rne(acc.x);
    r.y = f32_to_bf16_rne(acc.y);
    r.z = f32_to_bf16_rne(acc.z);
    r.w = f32_to_bf16_rne(acc.w);
    *(ushort4*)(weff + (long)o * 1024 + i0) = r;
}

// f32 variant for the fallback path
__global__ __launch_bounds__(256)
void weff_f32_kernel(const float* __restrict__ W, const float* __restrict__ up_aux,
                     const float* __restrict__ t2, float* __restrict__ weff) {
    int o = blockIdx.x;
    int i0 = threadIdx.x * 4;
    float4 acc = *(const float4*)(W + (long)o * 1024 + i0);
    for (int u = 0; u < 50; ++u) {
        float s = up_aux[o * 50 + u] * ALPHA;
        float4 t = *(const float4*)(t2 + u * 1024 + i0);
        acc.x += s * t.x; acc.y += s * t.y; acc.z += s * t.z; acc.w += s * t.w;
    }
    *(float4*)(weff + (long)o * 1024 + i0) = acc;
}

// ---------------------------------------------------------------------------
// Step 2: convert hidden_states f32 -> bf16 (vectorized, grid-stride)
__global__ __launch_bounds__(256)
void cvt_bf16_kernel(const float* __restrict__ in, unsigned short* __restrict__ out, long n4) {
    long idx = (long)blockIdx.x * blockDim.x + threadIdx.x;
    long stride = (long)gridDim.x * blockDim.x;
    for (long i = idx; i < n4; i += stride) {
        float4 v = ((const float4*)in)[i];
        ushort4 r;
        r.x = f32_to_bf16_rne(v.x);
        r.y = f32_to_bf16_rne(v.y);
        r.z = f32_to_bf16_rne(v.z);
        r.w = f32_to_bf16_rne(v.w);
        ((ushort4*)out)[i] = r;
    }
}

// ---------------------------------------------------------------------------
// Step 3: bf16 GEMM  C[M][N] = A[M][K] * Bt[N][K]^T + bias
// 128x128 tile, BK=32, 4 waves (2x2), each wave 64x64 = 4x4 fragments of 16x16x32.
#define BM 128
#define BN 128
#define BK 32

__global__ __launch_bounds__(256, 3)
void gemm_bt_bias_kernel(const unsigned short* __restrict__ A,
                         const unsigned short* __restrict__ Bt,
                         const float* __restrict__ bias,
                         float* __restrict__ C, int M, int N, int K) {
    __shared__ __align__(16) unsigned short As[BM * BK];  // 8 KB
    __shared__ __align__(16) unsigned short Bs[BN * BK];  // 8 KB

    int nTilesN = N / BN;
    int nwg = gridDim.x;
    int bid = blockIdx.x;
    // XCD-aware swizzle (bijective: nwg % 8 == 0 for this problem)
    int swz = bid;
    if ((nwg & 7) == 0) {
        int cpx = nwg >> 3;
        swz = (bid & 7) * cpx + (bid >> 3);
    }
    int tm = swz / nTilesN;
    int tn = swz % nTilesN;

    int tid = threadIdx.x;
    int lane = tid & 63;
    int wave = tid >> 6;   // 0..3
    int wr = wave >> 1;    // 0..1
    int wc = wave & 1;     // 0..1

    const long rowA0 = (long)tm * BM;
    const long colB0 = (long)tn * BN;

    // staging geometry: wave handles 32 rows (2 loads x 16 rows), lane l:
    // row = l>>2 within the 16-row group, col = (l&3)*8 bf16 elements
    int srow = (lane >> 2);
    int scol = (lane & 3) * 8;

    f32x4 acc[4][4];
#pragma unroll
    for (int m = 0; m < 4; ++m)
#pragma unroll
        for (int n = 0; n < 4; ++n) acc[m][n] = (f32x4)(0.0f);

    int fr = lane & 15;          // fragment row (A) / row of Bt (= col of B)
    int fk = (lane >> 4) * 8;    // fragment k offset

    for (int k0 = 0; k0 < K; k0 += BK) {
        __syncthreads();
        // stage A tile: rows [0,128) x cols [k0, k0+32)
#pragma unroll
        for (int j = 0; j < 2; ++j) {
            int r = wave * 32 + j * 16 + srow;
            const unsigned short* gp = A + (rowA0 + r) * (long)K + k0 + scol;
            unsigned short* lp = As + (wave * 32 + j * 16) * BK;  // wave-uniform base
            async_copy16(gp, lp);
        }
        // stage Bt tile
#pragma unroll
        for (int j = 0; j < 2; ++j) {
            int r = wave * 32 + j * 16 + srow;
            const unsigned short* gp = Bt + (colB0 + r) * (long)K + k0 + scol;
            unsigned short* lp = Bs + (wave * 32 + j * 16) * BK;
            async_copy16(gp, lp);
        }
        __syncthreads();

        bf16x8 a[4], b[4];
#pragma unroll
        for (int m = 0; m < 4; ++m)
            a[m] = *(const bf16x8*)(As + (wr * 64 + m * 16 + fr) * BK + fk);
#pragma unroll
        for (int n = 0; n < 4; ++n)
            b[n] = *(const bf16x8*)(Bs + (wc * 64 + n * 16 + fr) * BK + fk);
#pragma unroll
        for (int m = 0; m < 4; ++m)
#pragma unroll
            for (int n = 0; n < 4; ++n)
                acc[m][n] = __builtin_amdgcn_mfma_f32_16x16x32_bf16(a[m], b[n], acc[m][n], 0, 0, 0);
    }

    // epilogue: C[row][col] = acc + bias[col]
    int ccol = lane & 15;
    int crow = (lane >> 4) * 4;
#pragma unroll
    for (int m = 0; m < 4; ++m) {
        long grow = rowA0 + wr * 64 + m * 16 + crow;
#pragma unroll
        for (int n = 0; n < 4; ++n) {
            long gcol = colB0 + wc * 64 + n * 16 + ccol;
            float bb = bias[gcol];
#pragma unroll
            for (int r = 0; r < 4; ++r) {
                C[(grow + r) * N + gcol] = acc[m][n][r] + bb;
            }
        }
    }
}

// ---------------------------------------------------------------------------
// Fallback: plain f32 tiled GEMM (used only if ws too small for bf16 path)
__global__ __launch_bounds__(256)
void gemm_f32_fallback(const float* __restrict__ A, const float* __restrict__ Bt,
                       const float* __restrict__ bias, float* __restrict__ C,
                       int M, int N, int K) {
    __shared__ float As[64][17];
    __shared__ float Bs[64][17];
    int tilesN = N / 64;
    int tm = blockIdx.x / tilesN;
    int tn = blockIdx.x % tilesN;
    int tid = threadIdx.x;
    int tr = tid / 16, tc = tid % 16;
    float acc[4][4] = {};
    for (int k0 = 0; k0 < K; k0 += 16) {
        for (int t = tid; t < 64 * 16; t += 256) {
            int r = t / 16, c = t % 16;
            As[r][c] = A[((long)tm * 64 + r) * K + k0 + c];
            Bs[r][c] = Bt[((long)tn * 64 + r) * K + k0 + c];
        }
        __syncthreads();
#pragma unroll
        for (int kk = 0; kk < 16; ++kk) {
            float av[4], bv[4];
#pragma unroll
            for (int i = 0; i < 4; ++i) av[i] = As[tr * 4 + i][kk];
#pragma unroll
            for (int j = 0; j < 4; ++j) bv[j] = Bs[tc * 4 + j][kk];
#pragma unroll
            for (int i = 0; i < 4; ++i)
#pragma unroll
                for (int j = 0; j < 4; ++j) acc[i][j] += av[i] * bv[j];
        }
        __syncthreads();
    }
#pragma unroll
    for (int i = 0; i < 4; ++i) {
        long row = (long)tm * 64 + tr * 4 + i;
#pragma unroll
        for (int j = 0; j < 4; ++j) {
            long col = (long)tn * 64 + tc * 4 + j;
            C[row * N + col] = acc[i][j] + bias[col];
        }
    }
}

// ---------------------------------------------------------------------------
extern "C" void kernel_launch(void* const* d_in, const int* in_sizes, int n_in,
                              void* d_out, int out_size, void* d_ws, size_t ws_size,
                              hipStream_t stream) {
    const float* hs        = (const float*)d_in[0];
    const float* W         = (const float*)d_in[1];
    const float* b         = (const float*)d_in[2];
    const float* lora_down = (const float*)d_in[3];
    const float* lora_up   = (const float*)d_in[4];
    const float* down_aux  = (const float*)d_in[5];
    const float* up_aux    = (const float*)d_in[6];
    float* out = (float*)d_out;

    const int K = 1024;   // IN
    const int N = 1024;   // OUT
    const int M = in_sizes[0] / K;  // B*S = 65536

    char* ws = (char*)d_ws;
    // layout: t2 f32 [50*1024] @0 ; weff @256KB ; hs_bf16 @256KB+2MB
    float* t2 = (float*)ws;
    const size_t OFF_WEFF = 256 * 1024;
    const size_t OFF_HSBF = OFF_WEFF + 2 * 1024 * 1024;
    const size_t NEED_FAST = OFF_HSBF + (size_t)M * K * sizeof(unsigned short);

    // Step 1a: t2
    lilora_t2_kernel<<<1, 1024, 0, stream>>>(lora_down, lora_up, down_aux, t2);

    if (ws_size >= NEED_FAST) {
        unsigned short* weff = (unsigned short*)(ws + OFF_WEFF);
        unsigned short* hsbf = (unsigned short*)(ws + OFF_HSBF);
        // Step 1b: W_eff bf16
        weff_bf16_kernel<<<N, 256, 0, stream>>>(W, up_aux, t2, weff);
        // Step 2: hs -> bf16
        long n4 = (long)M * K / 4;
        cvt_bf16_kernel<<<4096, 256, 0, stream>>>(hs, hsbf, n4);
        // Step 3: GEMM
        int grid = (M / BM) * (N / BN);
        gemm_bt_bias_kernel<<<grid, 256, 0, stream>>>(hsbf, weff, b, out, M, N, K);
    } else {
        // fallback: f32 path (needs ~4.3 MB ws)
        float* weff = (float*)(ws + OFF_WEFF);
        weff_f32_kernel<<<N, 256, 0, stream>>>(W, up_aux, t2, weff);
        int grid = (M / 64) * (N / 64);
        gemm_f32_fallback<<<grid, 256, 0, stream>>>(hs, weff, b, out, M, N, K);
    }
}